// Round 2
// baseline (688.322 us; speedup 1.0000x reference)
//
#include <hip/hip_runtime.h>
#include <stdint.h>

#define HW_   65536
#define B_    4
#define C_    256
#define P_    256
#define TH_   0.8f
#define EPS_  1e-5f

#define CHUNK_  4096           // elements per phase-1 block
#define NCHUNK_ (HW_ / CHUNK_) // 16 chunks per batch
#define NCAND_  (NCHUNK_ * P_) // 4096 candidates per batch in phase 2

// ---------------------------------------------------------------------------
// key: (float bits of thresholded edge) << 32 | (65535 - i)
// unsigned-descending == (value desc, index asc) == jax.lax.top_k order.
// Keys are distinct (index embedded) -> exact, deterministic selection.
// ---------------------------------------------------------------------------
__device__ __forceinline__ uint64_t make_key(float v, int i) {
    if (v < TH_) v = 0.0f;
    return ((uint64_t)__float_as_uint(v) << 32) | (uint32_t)(65535 - i);
}

__device__ __forceinline__ uint64_t shfl_xor_u64(uint64_t v, int mask) {
    int lo = __shfl_xor((int)(uint32_t)v, mask, 64);
    int hi = __shfl_xor((int)(uint32_t)(v >> 32), mask, 64);
    return ((uint64_t)(uint32_t)hi << 32) | (uint32_t)lo;
}

// compare-exchange: after call, a holds the larger if desc else the smaller
__device__ __forceinline__ void ce(uint64_t &a, uint64_t &b, bool desc) {
    uint64_t x = a, y = b;
    bool sw = desc ? (x < y) : (x > y);
    a = sw ? y : x;
    b = sw ? x : y;
}

// cross-lane CE on all 16 elements; partner lane = lane ^ mask.
// want_max: this thread keeps the max of (mine, partner's) else the min.
__device__ __forceinline__ void lane_ce16(uint64_t kk[16], int mask, bool want_max) {
    #pragma unroll
    for (int e = 0; e < 16; ++e) {
        uint64_t o = shfl_xor_u64(kk[e], mask);
        kk[e] = (want_max == (kk[e] > o)) ? kk[e] : o;
    }
}

// intra-thread CE with direction depending on element bit (stages k<=8)
template<int K, int J>
__device__ __forceinline__ void intra_ce_k(uint64_t kk[16]) {
    #pragma unroll
    for (int e = 0; e < 16; ++e)
        if (!(e & J)) ce(kk[e], kk[e | J], ((e & K) == 0));
}

// intra-thread CE with uniform direction (stages k>=16)
template<int J>
__device__ __forceinline__ void intra_ce(uint64_t kk[16], bool d) {
    #pragma unroll
    for (int e = 0; e < 16; ++e)
        if (!(e & J)) ce(kk[e], kk[e | J], d);
}

// Sort each 256-element run DESC. Run = 16 consecutive threads x 16 elements,
// virtual index v = t*16 + e. Standard bitonic build, final stage forced desc.
__device__ __forceinline__ void sort256_desc(uint64_t kk[16], int t) {
    // k = 2, 4, 8 : intra-thread, direction from element bits
    intra_ce_k<2, 1>(kk);
    intra_ce_k<4, 2>(kk); intra_ce_k<4, 1>(kk);
    intra_ce_k<8, 4>(kk); intra_ce_k<8, 2>(kk); intra_ce_k<8, 1>(kk);
    // k = 16 : one thread's 16 els, dir from v&16 = t&1
    {
        const bool d = ((t & 1) == 0);
        intra_ce<8>(kk, d); intra_ce<4>(kk, d); intra_ce<2>(kk, d); intra_ce<1>(kk, d);
    }
    // k = 32 : dir from t&2 ; j=16 lane step then intra
    {
        const bool d = ((t & 2) == 0);
        lane_ce16(kk, 1, ((t & 1) == 0) == d);
        intra_ce<8>(kk, d); intra_ce<4>(kk, d); intra_ce<2>(kk, d); intra_ce<1>(kk, d);
    }
    // k = 64 : dir from t&4
    {
        const bool d = ((t & 4) == 0);
        lane_ce16(kk, 2, ((t & 2) == 0) == d);
        lane_ce16(kk, 1, ((t & 1) == 0) == d);
        intra_ce<8>(kk, d); intra_ce<4>(kk, d); intra_ce<2>(kk, d); intra_ce<1>(kk, d);
    }
    // k = 128 : dir from t&8
    {
        const bool d = ((t & 8) == 0);
        lane_ce16(kk, 4, ((t & 4) == 0) == d);
        lane_ce16(kk, 2, ((t & 2) == 0) == d);
        lane_ce16(kk, 1, ((t & 1) == 0) == d);
        intra_ce<8>(kk, d); intra_ce<4>(kk, d); intra_ce<2>(kk, d); intra_ce<1>(kk, d);
    }
    // k = 256 : final stage, force DESC for every run
    lane_ce16(kk, 8, ((t & 8) == 0));
    lane_ce16(kk, 4, ((t & 4) == 0));
    lane_ce16(kk, 2, ((t & 2) == 0));
    lane_ce16(kk, 1, ((t & 1) == 0));
    intra_ce<8>(kk, true); intra_ce<4>(kk, true); intra_ce<2>(kk, true); intra_ce<1>(kk, true);
}

// bitonic -> sorted DESC within each run of (16 lanes x 16 els)
__device__ __forceinline__ void merge_desc(uint64_t kk[16], int t) {
    lane_ce16(kk, 8, ((t & 8) == 0));
    lane_ce16(kk, 4, ((t & 4) == 0));
    lane_ce16(kk, 2, ((t & 2) == 0));
    lane_ce16(kk, 1, ((t & 1) == 0));
    intra_ce<8>(kk, true); intra_ce<4>(kk, true); intra_ce<2>(kk, true); intra_ce<1>(kk, true);
}

// top-256 of two DESC runs: C[i] = max(A[i], B[255-i]); partner lane = lane^maskL,
// partner element = 15-e. Valid (top) result lands in the A-run's lane positions;
// other lanes hold the reversed complement (unused). Result is bitonic.
__device__ __forceinline__ void maxmerge(uint64_t kk[16], int maskL) {
    uint64_t oth[16];
    #pragma unroll
    for (int e = 0; e < 16; ++e)
        oth[e] = shfl_xor_u64(kk[15 - e], maskL);
    #pragma unroll
    for (int e = 0; e < 16; ++e)
        kk[e] = kk[e] > oth[e] ? kk[e] : oth[e];
}

// ---------------------------------------------------------------------------
// phase 1: each block reduces a 4096-chunk to its exact top-256 (sorted desc).
// Register/shuffle bitonic: ONE __syncthreads total (vs 78 in the full sort).
// ---------------------------------------------------------------------------
__global__ __launch_bounds__(256) void topk_local_kernel(const float* __restrict__ edge,
                                                         uint64_t* __restrict__ cand) {
    __shared__ uint64_t lds[1024];
    const int b = blockIdx.y;
    const int chunk = blockIdx.x;
    const int t = threadIdx.x;          // 256 threads = 4 waves; 16 keys/thread
    const int base = chunk * CHUNK_;

    uint64_t kk[16];
    const float4* ep = (const float4*)(edge + (size_t)b * HW_ + base + t * 16);
    #pragma unroll
    for (int q = 0; q < 4; ++q) {
        const float4 f = ep[q];
        const int i0 = base + t * 16 + q * 4;
        kk[q * 4 + 0] = make_key(f.x, i0 + 0);
        kk[q * 4 + 1] = make_key(f.y, i0 + 1);
        kk[q * 4 + 2] = make_key(f.z, i0 + 2);
        kk[q * 4 + 3] = make_key(f.w, i0 + 3);
    }

    // 16 runs of 256, 4 per wave; sort each run desc (all in registers/shuffles)
    sort256_desc(kk, t);
    // per-wave reduction 1024 -> 256: pair(0,1)&(2,3) then pair(01,23)
    maxmerge(kk, 31); merge_desc(kk, t);   // lanes 0-15 / 32-47 of wave hold survivors
    maxmerge(kk, 47); merge_desc(kk, t);   // lanes 0-15 of wave hold wave top-256

    const int w = t >> 6, la = t & 63;
    if (la < 16) {
        #pragma unroll
        for (int e = 0; e < 16; ++e) lds[w * 256 + la * 16 + e] = kk[e];
    }
    __syncthreads();

    if (t < 64) {   // wave 0 reduces 4 wave-runs -> chunk top-256
        #pragma unroll
        for (int e = 0; e < 16; ++e) kk[e] = lds[t * 16 + e];
        maxmerge(kk, 31); merge_desc(kk, t);
        maxmerge(kk, 47); merge_desc(kk, t);
        if (t < 16) {
            #pragma unroll
            for (int e = 0; e < 16; ++e)
                cand[((size_t)(b * NCHUNK_ + chunk)) * P_ + t * 16 + e] = kk[e];
        }
    }
}

// ---------------------------------------------------------------------------
// phase 2: one block per batch merges 16 pre-sorted runs -> exact top-256,
// sorted desc (== jax.lax.top_k order). Merge rounds only, no initial sort.
// ---------------------------------------------------------------------------
__global__ __launch_bounds__(256) void topk_merge_kernel(const uint64_t* __restrict__ cand,
                                                         int* __restrict__ idx_out) {
    __shared__ uint64_t lds[1024];
    const int b = blockIdx.x;
    const int t = threadIdx.x;

    uint64_t kk[16];
    #pragma unroll
    for (int e = 0; e < 16; ++e) kk[e] = cand[(size_t)b * NCAND_ + t * 16 + e];

    maxmerge(kk, 31); merge_desc(kk, t);
    maxmerge(kk, 47); merge_desc(kk, t);

    const int w = t >> 6, la = t & 63;
    if (la < 16) {
        #pragma unroll
        for (int e = 0; e < 16; ++e) lds[w * 256 + la * 16 + e] = kk[e];
    }
    __syncthreads();

    if (t < 64) {
        #pragma unroll
        for (int e = 0; e < 16; ++e) kk[e] = lds[t * 16 + e];
        maxmerge(kk, 31); merge_desc(kk, t);
        maxmerge(kk, 47); merge_desc(kk, t);
        if (t < 16) {
            #pragma unroll
            for (int e = 0; e < 16; ++e)
                idx_out[b * P_ + t * 16 + e] = 65535 - (int)(kk[e] & 0xFFFFFFFFull);
        }
    }
}

// ---------------------------------------------------------------------------
// bulk copy out = x : 512 MB HBM traffic, the structural floor (~85 us @6.3TB/s)
// ---------------------------------------------------------------------------
__global__ __launch_bounds__(256) void copy_kernel(const float4* __restrict__ src,
                                                   float4* __restrict__ dst, int n4) {
    int i = blockIdx.x * 256 + threadIdx.x;
    const int stride = gridDim.x * 256;
    for (; i < n4; i += stride) dst[i] = src[i];
}

// ---------------------------------------------------------------------------
// gather: feat[b][n][d] = x[b][d][idx[b][n]]   (B,P,C) row-major
// ---------------------------------------------------------------------------
__global__ __launch_bounds__(256) void gather_kernel(const float* __restrict__ x,
                                                     const int* __restrict__ idx,
                                                     float* __restrict__ feat) {
    const int bn = blockIdx.x;           // b*P_ + n
    const int d = threadIdx.x;           // 0..255
    const int b = bn >> 8;
    const int hw = idx[bn];              // broadcast (scalar) load
    feat[(size_t)bn * C_ + d] = x[((size_t)(b * C_ + d)) * HW_ + hw];
}

// ---------------------------------------------------------------------------
// stage 1: z = relu(bn_adj(w_adj @ feat)) + feat      (per batch, 256x256x256)
// 64x64 tile / block, 256 threads, 4x4 microtile
// ---------------------------------------------------------------------------
__global__ __launch_bounds__(256) void mm1_kernel(const float* __restrict__ w_adj,
                                                  const float* __restrict__ feat,
                                                  const float* __restrict__ g,
                                                  const float* __restrict__ bb,
                                                  const float* __restrict__ m,
                                                  const float* __restrict__ vv,
                                                  float* __restrict__ z) {
    __shared__ __align__(16) float a_s[64][68];
    __shared__ __align__(16) float b_s[64][68];
    const int b = blockIdx.y;
    const int i0 = (blockIdx.x >> 2) * 64;
    const int d0 = (blockIdx.x & 3) * 64;
    const int tid = threadIdx.x;
    const int tx = tid & 15, ty = tid >> 4;
    const float* fb = feat + (size_t)b * P_ * C_;

    float acc[4][4] = {};
    for (int k0 = 0; k0 < 256; k0 += 64) {
        for (int l = tid; l < 4096; l += 256) {
            int r = l >> 6, c = l & 63;
            a_s[r][c] = w_adj[(i0 + r) * 256 + (k0 + c)];
            b_s[r][c] = fb[(size_t)(k0 + r) * 256 + (d0 + c)];
        }
        __syncthreads();
        #pragma unroll
        for (int kk = 0; kk < 64; kk += 4) {
            float4 a4[4], b4[4];
            #pragma unroll
            for (int r = 0; r < 4; ++r) a4[r] = *(const float4*)&a_s[ty * 4 + r][kk];
            #pragma unroll
            for (int j = 0; j < 4; ++j) b4[j] = *(const float4*)&b_s[kk + j][tx * 4];
            #pragma unroll
            for (int r = 0; r < 4; ++r) {
                const float4 av = a4[r];
                const float aj0 = av.x, aj1 = av.y, aj2 = av.z, aj3 = av.w;
                acc[r][0] = fmaf(aj0, b4[0].x, acc[r][0]);
                acc[r][1] = fmaf(aj0, b4[0].y, acc[r][1]);
                acc[r][2] = fmaf(aj0, b4[0].z, acc[r][2]);
                acc[r][3] = fmaf(aj0, b4[0].w, acc[r][3]);
                acc[r][0] = fmaf(aj1, b4[1].x, acc[r][0]);
                acc[r][1] = fmaf(aj1, b4[1].y, acc[r][1]);
                acc[r][2] = fmaf(aj1, b4[1].z, acc[r][2]);
                acc[r][3] = fmaf(aj1, b4[1].w, acc[r][3]);
                acc[r][0] = fmaf(aj2, b4[2].x, acc[r][0]);
                acc[r][1] = fmaf(aj2, b4[2].y, acc[r][1]);
                acc[r][2] = fmaf(aj2, b4[2].z, acc[r][2]);
                acc[r][3] = fmaf(aj2, b4[2].w, acc[r][3]);
                acc[r][0] = fmaf(aj3, b4[3].x, acc[r][0]);
                acc[r][1] = fmaf(aj3, b4[3].y, acc[r][1]);
                acc[r][2] = fmaf(aj3, b4[3].z, acc[r][2]);
                acc[r][3] = fmaf(aj3, b4[3].w, acc[r][3]);
            }
        }
        __syncthreads();
    }
    #pragma unroll
    for (int r = 0; r < 4; ++r) {
        const int i = i0 + ty * 4 + r;
        const float inv = g[i] / sqrtf(vv[i] + EPS_);
        const float beta = bb[i] - m[i] * inv;
        const int d = d0 + tx * 4;
        float4 res = *(const float4*)&fb[(size_t)i * 256 + d];
        float4 o;
        o.x = fmaxf(acc[r][0] * inv + beta, 0.0f) + res.x;
        o.y = fmaxf(acc[r][1] * inv + beta, 0.0f) + res.y;
        o.z = fmaxf(acc[r][2] * inv + beta, 0.0f) + res.z;
        o.w = fmaxf(acc[r][3] * inv + beta, 0.0f) + res.w;
        *(float4*)&z[((size_t)b * P_ + i) * C_ + d] = o;
    }
}

// ---------------------------------------------------------------------------
// stage 2 + scatter: out[b][c][idx[b][p]] = relu(bn_wg(sum_d w_wg[c][d]*z[b][p][d]))
// ---------------------------------------------------------------------------
__global__ __launch_bounds__(256) void mm2_kernel(const float* __restrict__ w_wg,
                                                  const float* __restrict__ z,
                                                  const int* __restrict__ idx,
                                                  const float* __restrict__ g,
                                                  const float* __restrict__ bb,
                                                  const float* __restrict__ m,
                                                  const float* __restrict__ vv,
                                                  float* __restrict__ out) {
    __shared__ __align__(16) float a_s[64][68];
    __shared__ __align__(16) float bt_s[64][68];   // bt_s[d][p] = z[p][d]
    const int b = blockIdx.y;
    const int c0 = (blockIdx.x >> 2) * 64;
    const int p0 = (blockIdx.x & 3) * 64;
    const int tid = threadIdx.x;
    const int tx = tid & 15, ty = tid >> 4;
    const float* zb = z + (size_t)b * P_ * C_;

    float acc[4][4] = {};
    for (int k0 = 0; k0 < 256; k0 += 64) {
        for (int l = tid; l < 4096; l += 256) {
            int r = l >> 6, c = l & 63;
            a_s[r][c] = w_wg[(c0 + r) * 256 + (k0 + c)];
            bt_s[c][r] = zb[(size_t)(p0 + r) * 256 + (k0 + c)];
        }
        __syncthreads();
        #pragma unroll
        for (int kk = 0; kk < 64; kk += 4) {
            float4 a4[4], b4[4];
            #pragma unroll
            for (int r = 0; r < 4; ++r) a4[r] = *(const float4*)&a_s[ty * 4 + r][kk];
            #pragma unroll
            for (int j = 0; j < 4; ++j) b4[j] = *(const float4*)&bt_s[kk + j][tx * 4];
            #pragma unroll
            for (int r = 0; r < 4; ++r) {
                const float4 av = a4[r];
                const float aj0 = av.x, aj1 = av.y, aj2 = av.z, aj3 = av.w;
                acc[r][0] = fmaf(aj0, b4[0].x, acc[r][0]);
                acc[r][1] = fmaf(aj0, b4[0].y, acc[r][1]);
                acc[r][2] = fmaf(aj0, b4[0].z, acc[r][2]);
                acc[r][3] = fmaf(aj0, b4[0].w, acc[r][3]);
                acc[r][0] = fmaf(aj1, b4[1].x, acc[r][0]);
                acc[r][1] = fmaf(aj1, b4[1].y, acc[r][1]);
                acc[r][2] = fmaf(aj1, b4[1].z, acc[r][2]);
                acc[r][3] = fmaf(aj1, b4[1].w, acc[r][3]);
                acc[r][0] = fmaf(aj2, b4[2].x, acc[r][0]);
                acc[r][1] = fmaf(aj2, b4[2].y, acc[r][1]);
                acc[r][2] = fmaf(aj2, b4[2].z, acc[r][2]);
                acc[r][3] = fmaf(aj2, b4[2].w, acc[r][3]);
                acc[r][0] = fmaf(aj3, b4[3].x, acc[r][0]);
                acc[r][1] = fmaf(aj3, b4[3].y, acc[r][1]);
                acc[r][2] = fmaf(aj3, b4[3].z, acc[r][2]);
                acc[r][3] = fmaf(aj3, b4[3].w, acc[r][3]);
            }
        }
        __syncthreads();
    }
    int pidx[4];
    #pragma unroll
    for (int cc = 0; cc < 4; ++cc) pidx[cc] = idx[b * P_ + p0 + tx * 4 + cc];
    #pragma unroll
    for (int r = 0; r < 4; ++r) {
        const int c = c0 + ty * 4 + r;
        const float inv = g[c] / sqrtf(vv[c] + EPS_);
        const float beta = bb[c] - m[c] * inv;
        float* orow = out + ((size_t)(b * C_ + c)) * HW_;
        #pragma unroll
        for (int cc = 0; cc < 4; ++cc) {
            orow[pidx[cc]] = fmaxf(acc[r][cc] * inv + beta, 0.0f);
        }
    }
}

// ---------------------------------------------------------------------------
extern "C" void kernel_launch(void* const* d_in, const int* in_sizes, int n_in,
                              void* d_out, int out_size, void* d_ws, size_t ws_size,
                              hipStream_t stream) {
    const float* x     = (const float*)d_in[0];
    const float* edge  = (const float*)d_in[1];
    const float* w_adj = (const float*)d_in[2];
    const float* g_a   = (const float*)d_in[3];
    const float* b_a   = (const float*)d_in[4];
    const float* m_a   = (const float*)d_in[5];
    const float* v_a   = (const float*)d_in[6];
    const float* w_wg  = (const float*)d_in[7];
    const float* g_w   = (const float*)d_in[8];
    const float* b_w   = (const float*)d_in[9];
    const float* m_w   = (const float*)d_in[10];
    const float* v_w   = (const float*)d_in[11];
    float* out = (float*)d_out;

    // workspace layout
    char* ws = (char*)d_ws;
    int*      idx  = (int*)ws;                                       // 4 KB
    uint64_t* cand = (uint64_t*)(ws + 4096);                         // B*4096*8 = 128 KB
    float*    feat = (float*)(ws + 4096 + (size_t)B_ * NCAND_ * 8);  // 1 MB
    float*    z    = feat + (size_t)B_ * P_ * C_;                    // 1 MB

    // 1. bulk copy out = x (512 MB HBM traffic — structural floor)
    copy_kernel<<<4096, 256, 0, stream>>>((const float4*)x, (float4*)out,
                                          (int)((size_t)B_ * C_ * HW_ / 4));

    // 2. exact top-256 per batch (jax.lax.top_k order): register-bitonic top-k
    topk_local_kernel<<<dim3(NCHUNK_, B_), 256, 0, stream>>>(edge, cand);
    topk_merge_kernel<<<B_, 256, 0, stream>>>(cand, idx);

    // 3. gather feat (B,P,C)
    gather_kernel<<<B_ * P_, 256, 0, stream>>>(x, idx, feat);

    // 4. stage 1 GCN
    mm1_kernel<<<dim3(16, B_), 256, 0, stream>>>(w_adj, feat, g_a, b_a, m_a, v_a, z);

    // 5. stage 2 GCN + scatter into out
    mm2_kernel<<<dim3(16, B_), 256, 0, stream>>>(w_wg, z, idx, g_w, b_w, m_w, v_w, out);
}

// Round 3
// 580.085 us; speedup vs baseline: 1.1866x; 1.1866x over previous
//
#include <hip/hip_runtime.h>
#include <stdint.h>

#define HW_   65536
#define B_    4
#define C_    256
#define P_    256
#define TH_   0.8f
#define EPS_  1e-5f

#define CHUNK_  4096           // elements per phase-1 block
#define NCHUNK_ (HW_ / CHUNK_) // 16 chunks per batch
#define NCAND_  (NCHUNK_ * P_) // 4096 candidates per batch in phase 2

typedef float f4_t __attribute__((ext_vector_type(4)));

// ---------------------------------------------------------------------------
// key: (float bits of thresholded edge) << 32 | (65535 - i)
// unsigned-descending == (value desc, index asc) == jax.lax.top_k order.
// Keys are distinct (index embedded) -> exact, deterministic selection.
// ---------------------------------------------------------------------------
__device__ __forceinline__ uint64_t make_key(float v, int i) {
    if (v < TH_) v = 0.0f;
    return ((uint64_t)__float_as_uint(v) << 32) | (uint32_t)(65535 - i);
}

__device__ __forceinline__ uint64_t shfl_xor_u64(uint64_t v, int mask) {
    int lo = __shfl_xor((int)(uint32_t)v, mask, 64);
    int hi = __shfl_xor((int)(uint32_t)(v >> 32), mask, 64);
    return ((uint64_t)(uint32_t)hi << 32) | (uint32_t)lo;
}

// compare-exchange: after call, a holds the larger if desc else the smaller
__device__ __forceinline__ void ce(uint64_t &a, uint64_t &b, bool desc) {
    uint64_t x = a, y = b;
    bool sw = desc ? (x < y) : (x > y);
    a = sw ? y : x;
    b = sw ? x : y;
}

// cross-lane CE on all 16 elements; partner lane = lane ^ mask.
// want_max: this thread keeps the max of (mine, partner's) else the min.
__device__ __forceinline__ void lane_ce16(uint64_t kk[16], int mask, bool want_max) {
    #pragma unroll
    for (int e = 0; e < 16; ++e) {
        uint64_t o = shfl_xor_u64(kk[e], mask);
        kk[e] = (want_max == (kk[e] > o)) ? kk[e] : o;
    }
}

// intra-thread CE with direction depending on element bit (stages k<=8)
template<int K, int J>
__device__ __forceinline__ void intra_ce_k(uint64_t kk[16]) {
    #pragma unroll
    for (int e = 0; e < 16; ++e)
        if (!(e & J)) ce(kk[e], kk[e | J], ((e & K) == 0));
}

// intra-thread CE with uniform direction (stages k>=16)
template<int J>
__device__ __forceinline__ void intra_ce(uint64_t kk[16], bool d) {
    #pragma unroll
    for (int e = 0; e < 16; ++e)
        if (!(e & J)) ce(kk[e], kk[e | J], d);
}

// Sort each 256-element run DESC. Run = 16 consecutive threads x 16 elements,
// virtual index v = t*16 + e. Standard bitonic build, final stage forced desc.
__device__ __forceinline__ void sort256_desc(uint64_t kk[16], int t) {
    // k = 2, 4, 8 : intra-thread, direction from element bits
    intra_ce_k<2, 1>(kk);
    intra_ce_k<4, 2>(kk); intra_ce_k<4, 1>(kk);
    intra_ce_k<8, 4>(kk); intra_ce_k<8, 2>(kk); intra_ce_k<8, 1>(kk);
    // k = 16 : one thread's 16 els, dir from v&16 = t&1
    {
        const bool d = ((t & 1) == 0);
        intra_ce<8>(kk, d); intra_ce<4>(kk, d); intra_ce<2>(kk, d); intra_ce<1>(kk, d);
    }
    // k = 32 : dir from t&2 ; j=16 lane step then intra
    {
        const bool d = ((t & 2) == 0);
        lane_ce16(kk, 1, ((t & 1) == 0) == d);
        intra_ce<8>(kk, d); intra_ce<4>(kk, d); intra_ce<2>(kk, d); intra_ce<1>(kk, d);
    }
    // k = 64 : dir from t&4
    {
        const bool d = ((t & 4) == 0);
        lane_ce16(kk, 2, ((t & 2) == 0) == d);
        lane_ce16(kk, 1, ((t & 1) == 0) == d);
        intra_ce<8>(kk, d); intra_ce<4>(kk, d); intra_ce<2>(kk, d); intra_ce<1>(kk, d);
    }
    // k = 128 : dir from t&8
    {
        const bool d = ((t & 8) == 0);
        lane_ce16(kk, 4, ((t & 4) == 0) == d);
        lane_ce16(kk, 2, ((t & 2) == 0) == d);
        lane_ce16(kk, 1, ((t & 1) == 0) == d);
        intra_ce<8>(kk, d); intra_ce<4>(kk, d); intra_ce<2>(kk, d); intra_ce<1>(kk, d);
    }
    // k = 256 : final stage, force DESC for every run
    lane_ce16(kk, 8, ((t & 8) == 0));
    lane_ce16(kk, 4, ((t & 4) == 0));
    lane_ce16(kk, 2, ((t & 2) == 0));
    lane_ce16(kk, 1, ((t & 1) == 0));
    intra_ce<8>(kk, true); intra_ce<4>(kk, true); intra_ce<2>(kk, true); intra_ce<1>(kk, true);
}

// bitonic -> sorted DESC within each run of (16 lanes x 16 els)
__device__ __forceinline__ void merge_desc(uint64_t kk[16], int t) {
    lane_ce16(kk, 8, ((t & 8) == 0));
    lane_ce16(kk, 4, ((t & 4) == 0));
    lane_ce16(kk, 2, ((t & 2) == 0));
    lane_ce16(kk, 1, ((t & 1) == 0));
    intra_ce<8>(kk, true); intra_ce<4>(kk, true); intra_ce<2>(kk, true); intra_ce<1>(kk, true);
}

// top-256 of two DESC runs: C[i] = max(A[i], B[255-i]); partner lane = lane^maskL,
// partner element = 15-e. Valid (top) result lands in the A-run's lane positions;
// other lanes hold the reversed complement (unused). Result is bitonic.
__device__ __forceinline__ void maxmerge(uint64_t kk[16], int maskL) {
    uint64_t oth[16];
    #pragma unroll
    for (int e = 0; e < 16; ++e)
        oth[e] = shfl_xor_u64(kk[15 - e], maskL);
    #pragma unroll
    for (int e = 0; e < 16; ++e)
        kk[e] = kk[e] > oth[e] ? kk[e] : oth[e];
}

// ---------------------------------------------------------------------------
// phase 1: each block reduces a 4096-chunk to its exact top-256 (sorted desc).
// Register/shuffle bitonic: ONE __syncthreads total.
// ---------------------------------------------------------------------------
__global__ __launch_bounds__(256) void topk_local_kernel(const float* __restrict__ edge,
                                                         uint64_t* __restrict__ cand) {
    __shared__ uint64_t lds[1024];
    const int b = blockIdx.y;
    const int chunk = blockIdx.x;
    const int t = threadIdx.x;          // 256 threads = 4 waves; 16 keys/thread
    const int base = chunk * CHUNK_;

    uint64_t kk[16];
    const float4* ep = (const float4*)(edge + (size_t)b * HW_ + base + t * 16);
    #pragma unroll
    for (int q = 0; q < 4; ++q) {
        const float4 f = ep[q];
        const int i0 = base + t * 16 + q * 4;
        kk[q * 4 + 0] = make_key(f.x, i0 + 0);
        kk[q * 4 + 1] = make_key(f.y, i0 + 1);
        kk[q * 4 + 2] = make_key(f.z, i0 + 2);
        kk[q * 4 + 3] = make_key(f.w, i0 + 3);
    }

    // 16 runs of 256, 4 per wave; sort each run desc (all in registers/shuffles)
    sort256_desc(kk, t);
    // per-wave reduction 1024 -> 256: pair(0,1)&(2,3) then pair(01,23)
    maxmerge(kk, 31); merge_desc(kk, t);   // lanes 0-15 / 32-47 of wave hold survivors
    maxmerge(kk, 47); merge_desc(kk, t);   // lanes 0-15 of wave hold wave top-256

    const int w = t >> 6, la = t & 63;
    if (la < 16) {
        #pragma unroll
        for (int e = 0; e < 16; ++e) lds[w * 256 + la * 16 + e] = kk[e];
    }
    __syncthreads();

    if (t < 64) {   // wave 0 reduces 4 wave-runs -> chunk top-256
        #pragma unroll
        for (int e = 0; e < 16; ++e) kk[e] = lds[t * 16 + e];
        maxmerge(kk, 31); merge_desc(kk, t);
        maxmerge(kk, 47); merge_desc(kk, t);
        if (t < 16) {
            #pragma unroll
            for (int e = 0; e < 16; ++e)
                cand[((size_t)(b * NCHUNK_ + chunk)) * P_ + t * 16 + e] = kk[e];
        }
    }
}

// ---------------------------------------------------------------------------
// phase 2: one block per batch merges 16 pre-sorted runs -> exact top-256,
// sorted desc (== jax.lax.top_k order). Merge rounds only, no initial sort.
// ---------------------------------------------------------------------------
__global__ __launch_bounds__(256) void topk_merge_kernel(const uint64_t* __restrict__ cand,
                                                         int* __restrict__ idx_out) {
    __shared__ uint64_t lds[1024];
    const int b = blockIdx.x;
    const int t = threadIdx.x;

    uint64_t kk[16];
    #pragma unroll
    for (int e = 0; e < 16; ++e) kk[e] = cand[(size_t)b * NCAND_ + t * 16 + e];

    maxmerge(kk, 31); merge_desc(kk, t);
    maxmerge(kk, 47); merge_desc(kk, t);

    const int w = t >> 6, la = t & 63;
    if (la < 16) {
        #pragma unroll
        for (int e = 0; e < 16; ++e) lds[w * 256 + la * 16 + e] = kk[e];
    }
    __syncthreads();

    if (t < 64) {
        #pragma unroll
        for (int e = 0; e < 16; ++e) kk[e] = lds[t * 16 + e];
        maxmerge(kk, 31); merge_desc(kk, t);
        maxmerge(kk, 47); merge_desc(kk, t);
        if (t < 16) {
            #pragma unroll
            for (int e = 0; e < 16; ++e)
                idx_out[b * P_ + t * 16 + e] = 65535 - (int)(kk[e] & 0xFFFFFFFFull);
        }
    }
}

// ---------------------------------------------------------------------------
// bulk copy out = x : 537 MB HBM traffic, the structural floor (~85 us @6.3TB/s)
// nt hints: out is never re-read by us, x needn't be L2-retained. 4x unroll for
// a deeper VMEM queue.
// ---------------------------------------------------------------------------
__global__ __launch_bounds__(256) void copy_kernel(const f4_t* __restrict__ src,
                                                   f4_t* __restrict__ dst, int n4) {
    int i = blockIdx.x * 256 + threadIdx.x;
    const int stride = gridDim.x * 256;
    for (; i + 3 * stride < n4; i += 4 * stride) {
        f4_t v0 = __builtin_nontemporal_load(src + i);
        f4_t v1 = __builtin_nontemporal_load(src + i + stride);
        f4_t v2 = __builtin_nontemporal_load(src + i + 2 * stride);
        f4_t v3 = __builtin_nontemporal_load(src + i + 3 * stride);
        __builtin_nontemporal_store(v0, dst + i);
        __builtin_nontemporal_store(v1, dst + i + stride);
        __builtin_nontemporal_store(v2, dst + i + 2 * stride);
        __builtin_nontemporal_store(v3, dst + i + 3 * stride);
    }
    for (; i < n4; i += stride) {
        f4_t v = __builtin_nontemporal_load(src + i);
        __builtin_nontemporal_store(v, dst + i);
    }
}

// ---------------------------------------------------------------------------
// gather: feat[b][n][d] = x[b][d][idx[b][n]]   (B,P,C) row-major
// ---------------------------------------------------------------------------
__global__ __launch_bounds__(256) void gather_kernel(const float* __restrict__ x,
                                                     const int* __restrict__ idx,
                                                     float* __restrict__ feat) {
    const int bn = blockIdx.x;           // b*P_ + n
    const int d = threadIdx.x;           // 0..255
    const int b = bn >> 8;
    const int hw = idx[bn];              // broadcast (scalar) load
    feat[(size_t)bn * C_ + d] = x[((size_t)(b * C_ + d)) * HW_ + hw];
}

// ---------------------------------------------------------------------------
// stage 1: z = relu(bn_adj(w_adj @ feat)) + feat      (per batch, 256x256x256)
// 64x64 tile / block, 256 threads, 4x4 microtile; float4-vectorized staging
// ---------------------------------------------------------------------------
__global__ __launch_bounds__(256) void mm1_kernel(const float* __restrict__ w_adj,
                                                  const float* __restrict__ feat,
                                                  const float* __restrict__ g,
                                                  const float* __restrict__ bb,
                                                  const float* __restrict__ m,
                                                  const float* __restrict__ vv,
                                                  float* __restrict__ z) {
    __shared__ __align__(16) float a_s[64][68];
    __shared__ __align__(16) float b_s[64][68];
    const int b = blockIdx.y;
    const int i0 = (blockIdx.x >> 2) * 64;
    const int d0 = (blockIdx.x & 3) * 64;
    const int tid = threadIdx.x;
    const int tx = tid & 15, ty = tid >> 4;
    const float* fb = feat + (size_t)b * P_ * C_;

    float acc[4][4] = {};
    for (int k0 = 0; k0 < 256; k0 += 64) {
        // vectorized staging: 1024 float4s, 4 per thread, coalesced 256B rows
        for (int l = tid; l < 1024; l += 256) {
            const int r = l >> 4, c4 = (l & 15) << 2;
            *(float4*)&a_s[r][c4] = *(const float4*)&w_adj[(i0 + r) * 256 + (k0 + c4)];
            *(float4*)&b_s[r][c4] = *(const float4*)&fb[(size_t)(k0 + r) * 256 + (d0 + c4)];
        }
        __syncthreads();
        #pragma unroll
        for (int kk = 0; kk < 64; kk += 4) {
            float4 a4[4], b4[4];
            #pragma unroll
            for (int r = 0; r < 4; ++r) a4[r] = *(const float4*)&a_s[ty * 4 + r][kk];
            #pragma unroll
            for (int j = 0; j < 4; ++j) b4[j] = *(const float4*)&b_s[kk + j][tx * 4];
            #pragma unroll
            for (int r = 0; r < 4; ++r) {
                const float4 av = a4[r];
                const float aj0 = av.x, aj1 = av.y, aj2 = av.z, aj3 = av.w;
                acc[r][0] = fmaf(aj0, b4[0].x, acc[r][0]);
                acc[r][1] = fmaf(aj0, b4[0].y, acc[r][1]);
                acc[r][2] = fmaf(aj0, b4[0].z, acc[r][2]);
                acc[r][3] = fmaf(aj0, b4[0].w, acc[r][3]);
                acc[r][0] = fmaf(aj1, b4[1].x, acc[r][0]);
                acc[r][1] = fmaf(aj1, b4[1].y, acc[r][1]);
                acc[r][2] = fmaf(aj1, b4[1].z, acc[r][2]);
                acc[r][3] = fmaf(aj1, b4[1].w, acc[r][3]);
                acc[r][0] = fmaf(aj2, b4[2].x, acc[r][0]);
                acc[r][1] = fmaf(aj2, b4[2].y, acc[r][1]);
                acc[r][2] = fmaf(aj2, b4[2].z, acc[r][2]);
                acc[r][3] = fmaf(aj2, b4[2].w, acc[r][3]);
                acc[r][0] = fmaf(aj3, b4[3].x, acc[r][0]);
                acc[r][1] = fmaf(aj3, b4[3].y, acc[r][1]);
                acc[r][2] = fmaf(aj3, b4[3].z, acc[r][2]);
                acc[r][3] = fmaf(aj3, b4[3].w, acc[r][3]);
            }
        }
        __syncthreads();
    }
    #pragma unroll
    for (int r = 0; r < 4; ++r) {
        const int i = i0 + ty * 4 + r;
        const float inv = g[i] / sqrtf(vv[i] + EPS_);
        const float beta = bb[i] - m[i] * inv;
        const int d = d0 + tx * 4;
        float4 res = *(const float4*)&fb[(size_t)i * 256 + d];
        float4 o;
        o.x = fmaxf(acc[r][0] * inv + beta, 0.0f) + res.x;
        o.y = fmaxf(acc[r][1] * inv + beta, 0.0f) + res.y;
        o.z = fmaxf(acc[r][2] * inv + beta, 0.0f) + res.z;
        o.w = fmaxf(acc[r][3] * inv + beta, 0.0f) + res.w;
        *(float4*)&z[((size_t)b * P_ + i) * C_ + d] = o;
    }
}

// ---------------------------------------------------------------------------
// stage 2 + scatter: out[b][c][idx[b][p]] = relu(bn_wg(sum_d w_wg[c][d]*z[b][p][d]))
// transpose staging: float4 global load + 4 scalar LDS stores; store banks are
// (4m+r)%32 over the wave -> 2 lanes/bank = conflict-free (vs 8-way before)
// ---------------------------------------------------------------------------
__global__ __launch_bounds__(256) void mm2_kernel(const float* __restrict__ w_wg,
                                                  const float* __restrict__ z,
                                                  const int* __restrict__ idx,
                                                  const float* __restrict__ g,
                                                  const float* __restrict__ bb,
                                                  const float* __restrict__ m,
                                                  const float* __restrict__ vv,
                                                  float* __restrict__ out) {
    __shared__ __align__(16) float a_s[64][68];
    __shared__ __align__(16) float bt_s[64][68];   // bt_s[d][p] = z[p][d]
    const int b = blockIdx.y;
    const int c0 = (blockIdx.x >> 2) * 64;
    const int p0 = (blockIdx.x & 3) * 64;
    const int tid = threadIdx.x;
    const int tx = tid & 15, ty = tid >> 4;
    const float* zb = z + (size_t)b * P_ * C_;

    float acc[4][4] = {};
    for (int k0 = 0; k0 < 256; k0 += 64) {
        for (int l = tid; l < 1024; l += 256) {
            const int r = l >> 4, c4 = (l & 15) << 2;
            *(float4*)&a_s[r][c4] = *(const float4*)&w_wg[(c0 + r) * 256 + (k0 + c4)];
            const float4 v = *(const float4*)&zb[(size_t)(p0 + r) * 256 + (k0 + c4)];
            bt_s[c4 + 0][r] = v.x;
            bt_s[c4 + 1][r] = v.y;
            bt_s[c4 + 2][r] = v.z;
            bt_s[c4 + 3][r] = v.w;
        }
        __syncthreads();
        #pragma unroll
        for (int kk = 0; kk < 64; kk += 4) {
            float4 a4[4], b4[4];
            #pragma unroll
            for (int r = 0; r < 4; ++r) a4[r] = *(const float4*)&a_s[ty * 4 + r][kk];
            #pragma unroll
            for (int j = 0; j < 4; ++j) b4[j] = *(const float4*)&bt_s[kk + j][tx * 4];
            #pragma unroll
            for (int r = 0; r < 4; ++r) {
                const float4 av = a4[r];
                const float aj0 = av.x, aj1 = av.y, aj2 = av.z, aj3 = av.w;
                acc[r][0] = fmaf(aj0, b4[0].x, acc[r][0]);
                acc[r][1] = fmaf(aj0, b4[0].y, acc[r][1]);
                acc[r][2] = fmaf(aj0, b4[0].z, acc[r][2]);
                acc[r][3] = fmaf(aj0, b4[0].w, acc[r][3]);
                acc[r][0] = fmaf(aj1, b4[1].x, acc[r][0]);
                acc[r][1] = fmaf(aj1, b4[1].y, acc[r][1]);
                acc[r][2] = fmaf(aj1, b4[1].z, acc[r][2]);
                acc[r][3] = fmaf(aj1, b4[1].w, acc[r][3]);
                acc[r][0] = fmaf(aj2, b4[2].x, acc[r][0]);
                acc[r][1] = fmaf(aj2, b4[2].y, acc[r][1]);
                acc[r][2] = fmaf(aj2, b4[2].z, acc[r][2]);
                acc[r][3] = fmaf(aj2, b4[2].w, acc[r][3]);
                acc[r][0] = fmaf(aj3, b4[3].x, acc[r][0]);
                acc[r][1] = fmaf(aj3, b4[3].y, acc[r][1]);
                acc[r][2] = fmaf(aj3, b4[3].z, acc[r][2]);
                acc[r][3] = fmaf(aj3, b4[3].w, acc[r][3]);
            }
        }
        __syncthreads();
    }
    int pidx[4];
    #pragma unroll
    for (int cc = 0; cc < 4; ++cc) pidx[cc] = idx[b * P_ + p0 + tx * 4 + cc];
    #pragma unroll
    for (int r = 0; r < 4; ++r) {
        const int c = c0 + ty * 4 + r;
        const float inv = g[c] / sqrtf(vv[c] + EPS_);
        const float beta = bb[c] - m[c] * inv;
        float* orow = out + ((size_t)(b * C_ + c)) * HW_;
        #pragma unroll
        for (int cc = 0; cc < 4; ++cc) {
            orow[pidx[cc]] = fmaxf(acc[r][cc] * inv + beta, 0.0f);
        }
    }
}

// ---------------------------------------------------------------------------
extern "C" void kernel_launch(void* const* d_in, const int* in_sizes, int n_in,
                              void* d_out, int out_size, void* d_ws, size_t ws_size,
                              hipStream_t stream) {
    const float* x     = (const float*)d_in[0];
    const float* edge  = (const float*)d_in[1];
    const float* w_adj = (const float*)d_in[2];
    const float* g_a   = (const float*)d_in[3];
    const float* b_a   = (const float*)d_in[4];
    const float* m_a   = (const float*)d_in[5];
    const float* v_a   = (const float*)d_in[6];
    const float* w_wg  = (const float*)d_in[7];
    const float* g_w   = (const float*)d_in[8];
    const float* b_w   = (const float*)d_in[9];
    const float* m_w   = (const float*)d_in[10];
    const float* v_w   = (const float*)d_in[11];
    float* out = (float*)d_out;

    // workspace layout
    char* ws = (char*)d_ws;
    int*      idx  = (int*)ws;                                       // 4 KB
    uint64_t* cand = (uint64_t*)(ws + 4096);                         // B*4096*8 = 128 KB
    float*    feat = (float*)(ws + 4096 + (size_t)B_ * NCAND_ * 8);  // 1 MB
    float*    z    = feat + (size_t)B_ * P_ * C_;                    // 1 MB

    // 1. bulk copy out = x (537 MB HBM traffic — structural floor)
    copy_kernel<<<8192, 256, 0, stream>>>((const f4_t*)x, (f4_t*)out,
                                          (int)((size_t)B_ * C_ * HW_ / 4));

    // 2. exact top-256 per batch (jax.lax.top_k order): register-bitonic top-k
    topk_local_kernel<<<dim3(NCHUNK_, B_), 256, 0, stream>>>(edge, cand);
    topk_merge_kernel<<<B_, 256, 0, stream>>>(cand, idx);

    // 3. gather feat (B,P,C)
    gather_kernel<<<B_ * P_, 256, 0, stream>>>(x, idx, feat);

    // 4. stage 1 GCN
    mm1_kernel<<<dim3(16, B_), 256, 0, stream>>>(w_adj, feat, g_a, b_a, m_a, v_a, z);

    // 5. stage 2 GCN + scatter into out
    mm2_kernel<<<dim3(16, B_), 256, 0, stream>>>(w_wg, z, idx, g_w, b_w, m_w, v_w, out);
}